// Round 10
// baseline (368.985 us; speedup 1.0000x reference)
//
#include <hip/hip_runtime.h>

// FernSparseTable: B[64,160,32,32] f32, tables[16,1024,64] f32,
// out[64,32,32,64] f32 = sum over 16 ferns of 8-word weighted table gathers.
//
// Round-10: conflict-FREE gang-cooperative LDS gather.
//   Round-9 PMC: SQ_LDS_BANK_CONFLICT=2.87e7 (~13.7 extra cyc per ds_read_b128
//   on an 8-cyc floor) -- random per-lane rows => multinomial max-load over 8
//   bank-groups. Fix: block owns a 32-d half; row = 128B = one full bank sweep;
//   a gang of 8 lanes reads one row's 8x16B slots => every wave instr touches
//   each bank exactly 2x. Deterministically conflict-free.
//   - block = 1024 thr = 128 gangs x 8 lanes; gang owns 4 pixels; 512 px/block.
//   - grid = 128 px-groups x 2 d-halves = 256 blocks (1/CU). bid = h*128+pg
//     so both halves of a pixel group land on the same XCD (delta=128 = 0 mod 8).
//   - bit logic: lane computes px (gang*4 + (t&3)) once (lanes 4-7 mirror 0-3);
//     summary (base0,m0,m1,m2,p0,p1,p2) broadcast per-pixel via DPP quad_perm
//     (VALU pipe -- keeps the LDS pipe for gathers only).
//   - table slice staged via global_load_lds w16, LINEAR dest (no swizzle
//     needed -- layout is conflict-free already). Single 128KB buffer,
//     2 barriers/fern; stage(m+1) issued only after the read-done barrier.

#define NFERN 16
#define KBITS 10

typedef __attribute__((address_space(1))) const void GV;
typedef __attribute__((address_space(3))) void LV;
__device__ __forceinline__ void g2lds16(const void* g, void* l) {
    __builtin_amdgcn_global_load_lds((GV*)g, (LV*)l, 16u, 0, 0u);
}

// quad broadcast (lane (t&~3)+I) via DPP quad_perm -- VALU pipe, no LDS traffic
template<int I>
__device__ __forceinline__ unsigned qb_u(unsigned x) {
    return (unsigned)__builtin_amdgcn_mov_dpp((int)x, I | (I<<2) | (I<<4) | (I<<6),
                                              0xF, 0xF, false);
}
template<int I>
__device__ __forceinline__ float qb_f(float x) {
    int r = __builtin_amdgcn_mov_dpp(__builtin_bit_cast(int, x),
                                     I | (I<<2) | (I<<4) | (I<<6), 0xF, 0xF, false);
    return __builtin_bit_cast(float, r);
}

// process one of the gang's 4 pixels: broadcast summary from quad-lane I,
// reconstruct 8 words, conflict-free gather, FMA into acc.
template<int I>
__device__ __forceinline__ void do_px(const float* __restrict__ L, int sl,
                                      unsigned base0, unsigned m0, unsigned m1,
                                      unsigned m2, float p0, float p1, float p2,
                                      float4& acc) {
    const unsigned WB = qb_u<I>(base0);
    const unsigned M0 = qb_u<I>(m0), M1 = qb_u<I>(m1), M2 = qb_u<I>(m2);
    const float   P0 = qb_f<I>(p0),  P1 = qb_f<I>(p1),  P2 = qb_f<I>(p2);
    const float   Q0 = 1.f - P0,     Q1 = 1.f - P1,     Q2 = 1.f - P2;
    #pragma unroll
    for (int a = 0; a < 8; ++a) {
        const unsigned it = WB | ((a & 1) ? M0 : 0u)
                               | ((a & 2) ? M1 : 0u)
                               | ((a & 4) ? M2 : 0u);
        const float at = ((a & 1) ? P0 : Q0) * ((a & 2) ? P1 : Q1)
                       * ((a & 4) ? P2 : Q2);
        const float4 v = *(const float4*)(L + it * 32 + sl * 4);
        acc.x = fmaf(at, v.x, acc.x);
        acc.y = fmaf(at, v.y, acc.y);
        acc.z = fmaf(at, v.z, acc.z);
        acc.w = fmaf(at, v.w, acc.w);
    }
}

__global__ __launch_bounds__(1024, 4)
void fern_kernel(const float* __restrict__ B,
                 const float* __restrict__ tables,
                 float* __restrict__ out) {
    __shared__ __align__(16) float lds[1024 * 32];   // 128 KB: row r at r*32 floats

    const int t    = (int)threadIdx.x;
    const int bid  = (int)blockIdx.x;
    const int h    = bid >> 7;           // d-half: 0 -> d[0,32), 1 -> d[32,64)
    const int pg   = bid & 127;          // pixel group (512 px)
    const int gang = t >> 3;             // 0..127
    const int sl   = t & 7;              // slot within the 128B row
    const int qi   = t & 3;              // which of the gang's 4 px this lane computes

    const int px_gang = pg * 512 + gang * 4;
    const int mypx    = px_gang + qi;
    const int n  = mypx >> 10;           // uniform per block (512 px within one image)
    const int hw = mypx & 1023;
    const float* bptr = B + (size_t)n * (NFERN * KBITS * 1024) + hw;

    const float* tabh = tables + h * 32;

    float4 acc[4];
    #pragma unroll
    for (int i = 0; i < 4; ++i) acc[i] = make_float4(0.f, 0.f, 0.f, 0.f);

    // ---- prologue: stage fern 0 (linear dest: wave-uniform base + lane*16) ----
    #pragma unroll
    for (int k = 0; k < 8; ++k) {
        const int row = k * 128 + gang;
        g2lds16(tabh + (size_t)row * 64 + sl * 4, (char*)lds + k * 16384 + t * 16);
    }

    #pragma unroll 1
    for (int m = 0; m < NFERN; ++m) {
        // ---- phase A: bit logic for mypx (runs while staging is in flight) ----
        float tk[KBITS];
        #pragma unroll
        for (int k = 0; k < KBITS; ++k)
            tk[k] = bptr[(m * KBITS + k) * 1024];

        unsigned wb = 0u;
        #pragma unroll
        for (int k = 0; k < KBITS; ++k)
            wb = (wb << 1) | (tk[k] > 0.5f ? 1u : 0u);   // round-half-even: 0.5 -> 0

        int i0, i1, i2;
        float p0, p1, p2;
        {
            float bv = 1e30f; int bi = 0; float bpv = 0.f;
            #pragma unroll
            for (int k = 0; k < KBITS; ++k) {
                float v = fabsf(tk[k] - 0.5f);
                bool c = v < bv;
                bv = c ? v : bv;  bi = c ? k : bi;  bpv = c ? tk[k] : bpv;
            }
            i0 = bi; p0 = bpv;
        }
        {
            float bv = 1e30f; int bi = 0; float bpv = 0.f;
            #pragma unroll
            for (int k = 0; k < KBITS; ++k) {
                float v = (k == i0) ? 1e30f : fabsf(tk[k] - 0.5f);
                bool c = v < bv;
                bv = c ? v : bv;  bi = c ? k : bi;  bpv = c ? tk[k] : bpv;
            }
            i1 = bi; p1 = bpv;
        }
        {
            float bv = 1e30f; int bi = 0; float bpv = 0.f;
            #pragma unroll
            for (int k = 0; k < KBITS; ++k) {
                float v = (k == i0 || k == i1) ? 1e30f : fabsf(tk[k] - 0.5f);
                bool c = v < bv;
                bv = c ? v : bv;  bi = c ? k : bi;  bpv = c ? tk[k] : bpv;
            }
            i2 = bi; p2 = bpv;
        }

        const unsigned m0 = 1u << (KBITS - 1 - i0);
        const unsigned m1 = 1u << (KBITS - 1 - i1);
        const unsigned m2 = 1u << (KBITS - 1 - i2);
        const unsigned base0 = wb & ~(m0 | m1 | m2);

        __syncthreads();   // staging(m) landed (vmcnt drained per-wave pre-barrier)

        // ---- phase B: 4 px x 8 words, conflict-free gang gather ----
        do_px<0>(lds, sl, base0, m0, m1, m2, p0, p1, p2, acc[0]);
        do_px<1>(lds, sl, base0, m0, m1, m2, p0, p1, p2, acc[1]);
        do_px<2>(lds, sl, base0, m0, m1, m2, p0, p1, p2, acc[2]);
        do_px<3>(lds, sl, base0, m0, m1, m2, p0, p1, p2, acc[3]);

        __syncthreads();   // all waves done reading the buffer

        // ---- stage fern m+1 (safe: every wave passed the read-done barrier) ----
        if (m + 1 < NFERN) {
            #pragma unroll
            for (int k = 0; k < 8; ++k) {
                const int row = k * 128 + gang;
                g2lds16(tabh + (size_t)(m + 1) * (1024 * 64) + (size_t)row * 64 + sl * 4,
                        (char*)lds + k * 16384 + t * 16);
            }
        }
    }

    // ---- store: gang lanes write 8x16B consecutive = 128B per pixel ----
    #pragma unroll
    for (int i = 0; i < 4; ++i) {
        float* op = out + (size_t)(px_gang + i) * 64 + h * 32 + sl * 4;
        *(float4*)op = acc[i];
    }
}

extern "C" void kernel_launch(void* const* d_in, const int* in_sizes, int n_in,
                              void* d_out, int out_size, void* d_ws, size_t ws_size,
                              hipStream_t stream) {
    const float* B      = (const float*)d_in[0];
    const float* tables = (const float*)d_in[1];
    float* out          = (float*)d_out;
    fern_kernel<<<dim3(256), dim3(1024), 0, stream>>>(B, tables, out);
}

// Round 13
// 141.544 us; speedup vs baseline: 2.6069x; 2.6069x over previous
//
#include <hip/hip_runtime.h>

// FernSparseTable: B[64,160,32,32] f32, tables[16,1024,64] f32,
// out[64,32,32,64] f32 = sum over 16 ferns of 8-word weighted table gathers.
//
// Round-13 = round-11/12 resubmission (infra timeouts; design unmeasured).
// Quad-gang conflict-light LDS gather in the HEALTHY staging regime.
//  Evidence:
//   r9  (per-lane random rows, d-octant, dbuf): 119us, conflicts 13.7cyc/instr.
//   r10 (gang-8 full-sweep, d-half, single buf): conflicts ~3cyc/instr (fix
//       VALIDATED) but FETCH 46->442MB: per-fern per-XCD staged set was 4MB
//       (= whole L2) -> thrash. RULE: per-fern per-XCD staged set << L2.
//  Design:
//   - gang = hardware quad (4 lanes); lane qi owns pixel gang*4+qi's bit logic
//     (dup 4x vs r9's 8x); summary broadcast via DPP quad_perm (r10-proven).
//   - d-quarter split: row chunk 64B; quad reads one random row's 4x16B slots
//     => per instr 16 quads over 2 bank-halves: Binomial(16,1/2) max ~9.6/8
//     = 1.2x floor (vs r9 2.7x). Dense packing, no swizzle anywhere.
//   - fern slice 1024x64B = 64KB, double-buffered (128KB), r9's proven
//     one-barrier-per-fern cadence. grid = 64 pg x 4 dq = 256 blocks;
//     bid = dq*64+pg -> same-pg blocks land on same XCD (delta 64 = 0 mod 8).
//     Per-fern per-XCD staged set = 4 dq x 64KB = 256KB << 4MB L2 (healthy).

#define NFERN 16
#define KBITS 10

typedef __attribute__((address_space(1))) const void GV;
typedef __attribute__((address_space(3))) void LV;
__device__ __forceinline__ void g2lds16(const void* g, void* l) {
    __builtin_amdgcn_global_load_lds((GV*)g, (LV*)l, 16u, 0, 0u);
}

// quad broadcast (lane (t&~3)+I) via DPP quad_perm -- VALU pipe, no LDS traffic
template<int I>
__device__ __forceinline__ unsigned qb_u(unsigned x) {
    return (unsigned)__builtin_amdgcn_mov_dpp((int)x, I | (I<<2) | (I<<4) | (I<<6),
                                              0xF, 0xF, false);
}
template<int I>
__device__ __forceinline__ float qb_f(float x) {
    int r = __builtin_amdgcn_mov_dpp(__builtin_bit_cast(int, x),
                                     I | (I<<2) | (I<<4) | (I<<6), 0xF, 0xF, false);
    return __builtin_bit_cast(float, r);
}

// pixel I of this quad: broadcast its summary, gather 8 words, FMA into acc.
template<int I>
__device__ __forceinline__ void do_px(const float* __restrict__ L, int sl,
                                      unsigned base0, unsigned m0, unsigned m1,
                                      unsigned m2, float p0, float p1, float p2,
                                      float4& acc) {
    const unsigned WB = qb_u<I>(base0);
    const unsigned M0 = qb_u<I>(m0), M1 = qb_u<I>(m1), M2 = qb_u<I>(m2);
    const float   P0 = qb_f<I>(p0),  P1 = qb_f<I>(p1),  P2 = qb_f<I>(p2);
    const float   Q0 = 1.f - P0,     Q1 = 1.f - P1,     Q2 = 1.f - P2;
    #pragma unroll
    for (int a = 0; a < 8; ++a) {
        const unsigned it = WB | ((a & 1) ? M0 : 0u)
                               | ((a & 2) ? M1 : 0u)
                               | ((a & 4) ? M2 : 0u);
        const float at = ((a & 1) ? P0 : Q0) * ((a & 2) ? P1 : Q1)
                       * ((a & 4) ? P2 : Q2);
        const float4 v = *(const float4*)(L + it * 16 + sl * 4);  // 64B chunk
        acc.x = fmaf(at, v.x, acc.x);
        acc.y = fmaf(at, v.y, acc.y);
        acc.z = fmaf(at, v.z, acc.z);
        acc.w = fmaf(at, v.w, acc.w);
    }
}

__global__ __launch_bounds__(1024, 4)
void fern_kernel(const float* __restrict__ B,
                 const float* __restrict__ tables,
                 float* __restrict__ out) {
    __shared__ __align__(16) float lds[2][1024 * 16];   // 2 x 64KB

    const int t    = (int)threadIdx.x;
    const int bid  = (int)blockIdx.x;
    const int dq   = bid >> 6;           // d-quarter: d = dq*16 .. +15
    const int pg   = bid & 63;           // pixel group == image index n
    const int gang = t >> 2;             // 0..255 (hardware quad)
    const int sl   = t & 3;              // 16B slot within the 64B row chunk
    const int qi   = t & 3;              // which of the quad's 4 px this lane owns

    const int px_gang = pg * 1024 + gang * 4;
    const int mypx    = px_gang + qi;
    const int hw      = mypx & 1023;     // mypx>>10 == pg (uniform per block)
    const float* bptr = B + (size_t)pg * (NFERN * KBITS * 1024) + hw;

    const float* tabq = tables + dq * 16;   // this block's d-quarter columns

    float4 acc0 = make_float4(0.f,0.f,0.f,0.f), acc1 = acc0, acc2 = acc0, acc3 = acc0;

    // stage fern m's d-quarter slice (1024 rows x 64B) into lds[buf].
    // dest linear (wave-uniform base + t*16); source: row (t>>2), slot (t&3).
    // 4 rounds x 16KB. No swizzle on either side (both-sides-or-neither).
    #define STAGE(mm, buf)                                                      \
        { const float* src_ = tabq + (size_t)(mm) * (1024 * 64);                \
          _Pragma("unroll")                                                     \
          for (int R = 0; R < 4; ++R) {                                         \
              const int row_ = R * 256 + (t >> 2);                              \
              g2lds16(src_ + (size_t)row_ * 64 + (t & 3) * 4,                   \
                      (char*)(&lds[buf][0]) + R * 16384 + t * 16);              \
          } }

    STAGE(0, 0);
    __syncthreads();   // vmcnt drained per-wave before barrier -> buf0 ready

    #pragma unroll 1
    for (int m = 0; m < NFERN; ++m) {
        // ---- prefetch fern m+1 into the other buffer (r9 cadence) ----
        if (m + 1 < NFERN) { STAGE(m + 1, (m + 1) & 1); }
        const float* L = &lds[m & 1][0];

        // ---- phase A: bit logic for this lane's own pixel (dup 4x) ----
        float tk[KBITS];
        #pragma unroll
        for (int k = 0; k < KBITS; ++k)
            tk[k] = bptr[(m * KBITS + k) * 1024];

        unsigned wb = 0u;
        #pragma unroll
        for (int k = 0; k < KBITS; ++k)
            wb = (wb << 1) | (tk[k] > 0.5f ? 1u : 0u);   // round-half-even: 0.5 -> 0

        int i0, i1, i2;
        float p0, p1, p2;
        {
            float bv = 1e30f; int bi = 0; float bpv = 0.f;
            #pragma unroll
            for (int k = 0; k < KBITS; ++k) {
                float v = fabsf(tk[k] - 0.5f);
                bool c = v < bv;
                bv = c ? v : bv;  bi = c ? k : bi;  bpv = c ? tk[k] : bpv;
            }
            i0 = bi; p0 = bpv;
        }
        {
            float bv = 1e30f; int bi = 0; float bpv = 0.f;
            #pragma unroll
            for (int k = 0; k < KBITS; ++k) {
                float v = (k == i0) ? 1e30f : fabsf(tk[k] - 0.5f);
                bool c = v < bv;
                bv = c ? v : bv;  bi = c ? k : bi;  bpv = c ? tk[k] : bpv;
            }
            i1 = bi; p1 = bpv;
        }
        {
            float bv = 1e30f; int bi = 0; float bpv = 0.f;
            #pragma unroll
            for (int k = 0; k < KBITS; ++k) {
                float v = (k == i0 || k == i1) ? 1e30f : fabsf(tk[k] - 0.5f);
                bool c = v < bv;
                bv = c ? v : bv;  bi = c ? k : bi;  bpv = c ? tk[k] : bpv;
            }
            i2 = bi; p2 = bpv;
        }

        const unsigned m0 = 1u << (KBITS - 1 - i0);
        const unsigned m1 = 1u << (KBITS - 1 - i1);
        const unsigned m2 = 1u << (KBITS - 1 - i2);
        const unsigned base0 = wb & ~(m0 | m1 | m2);

        // ---- phase B: 4 px x 8 words, quad-cooperative gather from buf[m&1] ----
        do_px<0>(L, sl, base0, m0, m1, m2, p0, p1, p2, acc0);
        do_px<1>(L, sl, base0, m0, m1, m2, p0, p1, p2, acc1);
        do_px<2>(L, sl, base0, m0, m1, m2, p0, p1, p2, acc2);
        do_px<3>(L, sl, base0, m0, m1, m2, p0, p1, p2, acc3);

        __syncthreads();   // reads of buf[m&1] done; prefetch into buf[(m+1)&1] landed
    }
    #undef STAGE

    // ---- store: quad writes 4x16B = 64B contiguous per pixel ----
    {
        float* op0 = out + (size_t)(px_gang + 0) * 64 + dq * 16 + sl * 4;
        float* op1 = out + (size_t)(px_gang + 1) * 64 + dq * 16 + sl * 4;
        float* op2 = out + (size_t)(px_gang + 2) * 64 + dq * 16 + sl * 4;
        float* op3 = out + (size_t)(px_gang + 3) * 64 + dq * 16 + sl * 4;
        *(float4*)op0 = acc0;
        *(float4*)op1 = acc1;
        *(float4*)op2 = acc2;
        *(float4*)op3 = acc3;
    }
}

extern "C" void kernel_launch(void* const* d_in, const int* in_sizes, int n_in,
                              void* d_out, int out_size, void* d_ws, size_t ws_size,
                              hipStream_t stream) {
    const float* B      = (const float*)d_in[0];
    const float* tables = (const float*)d_in[1];
    float* out          = (float*)d_out;
    fern_kernel<<<dim3(256), dim3(1024), 0, stream>>>(B, tables, out);
}

// Round 16
// 138.720 us; speedup vs baseline: 2.6599x; 1.0204x over previous
//
#include <hip/hip_runtime.h>

// FernSparseTable: B[64,160,32,32] f32, tables[16,1024,64] f32,
// out[64,32,32,64] f32 = sum over 16 ferns of 8-word weighted table gathers.
//
// Round-16 = round-14/15 resubmission (infra timeouts; design unmeasured).
// r13 + software pipelining of phase A (bit logic) with phase B (LDS gathers).
//  Evidence (r13, measured): dur 84us, LDS ~43us (12.6 cyc/gather incl 4.6
//  conflict), VALU ~40us (VALUBusy 53%), FETCH 36.9MB healthy. 43+40 ~= 84
//  => pipes SERIALIZED: all waves do A then B between the same barriers.
//  Fix: compute fern m+1's summary (VALU+VMEM, independent of staged buffer)
//  in the same window as fern m's gathers (LDS) -> per-wave overlap.
//  tk loads for m+1 issue a full window early -> latency hidden.
//  Everything else identical to r13 (validated: absmax 4.88e-4):
//   - quad gang (4 lanes), lane qi owns pixel gang*4+qi's logic; DPP quad_perm
//     broadcast; d-quarter split; 64KB slice double-buffered; 1 barrier/fern;
//     grid 64pg x 4dq = 256 blocks; per-fern/XCD staged set 256KB << L2.

#define NFERN 16
#define KBITS 10

typedef __attribute__((address_space(1))) const void GV;
typedef __attribute__((address_space(3))) void LV;
__device__ __forceinline__ void g2lds16(const void* g, void* l) {
    __builtin_amdgcn_global_load_lds((GV*)g, (LV*)l, 16u, 0, 0u);
}

// quad broadcast (lane (t&~3)+I) via DPP quad_perm -- VALU pipe, no LDS traffic
template<int I>
__device__ __forceinline__ unsigned qb_u(unsigned x) {
    return (unsigned)__builtin_amdgcn_mov_dpp((int)x, I | (I<<2) | (I<<4) | (I<<6),
                                              0xF, 0xF, false);
}
template<int I>
__device__ __forceinline__ float qb_f(float x) {
    int r = __builtin_amdgcn_mov_dpp(__builtin_bit_cast(int, x),
                                     I | (I<<2) | (I<<4) | (I<<6), 0xF, 0xF, false);
    return __builtin_bit_cast(float, r);
}

// phase A: load 10 bit-probs for fern m, compute word summary for this lane's px
__device__ __forceinline__ void phaseA(const float* __restrict__ bptr, int m,
                                       unsigned& base0, unsigned& m0o,
                                       unsigned& m1o, unsigned& m2o,
                                       float& p0o, float& p1o, float& p2o) {
    float tk[KBITS];
    #pragma unroll
    for (int k = 0; k < KBITS; ++k)
        tk[k] = bptr[(m * KBITS + k) * 1024];

    unsigned wb = 0u;
    float ab[KBITS];
    #pragma unroll
    for (int k = 0; k < KBITS; ++k) {
        wb = (wb << 1) | (tk[k] > 0.5f ? 1u : 0u);   // round-half-even: 0.5 -> 0
        ab[k] = fabsf(tk[k] - 0.5f);                 // hoisted: reused by 3 passes
    }

    int i0, i1, i2;
    float p0, p1, p2;
    {
        float bv = 1e30f; int bi = 0; float bpv = 0.f;
        #pragma unroll
        for (int k = 0; k < KBITS; ++k) {
            bool c = ab[k] < bv;
            bv = c ? ab[k] : bv;  bi = c ? k : bi;  bpv = c ? tk[k] : bpv;
        }
        i0 = bi; p0 = bpv;
    }
    {
        float bv = 1e30f; int bi = 0; float bpv = 0.f;
        #pragma unroll
        for (int k = 0; k < KBITS; ++k) {
            float v = (k == i0) ? 1e30f : ab[k];
            bool c = v < bv;
            bv = c ? v : bv;  bi = c ? k : bi;  bpv = c ? tk[k] : bpv;
        }
        i1 = bi; p1 = bpv;
    }
    {
        float bv = 1e30f; int bi = 0; float bpv = 0.f;
        #pragma unroll
        for (int k = 0; k < KBITS; ++k) {
            float v = (k == i0 || k == i1) ? 1e30f : ab[k];
            bool c = v < bv;
            bv = c ? v : bv;  bi = c ? k : bi;  bpv = c ? tk[k] : bpv;
        }
        i2 = bi; p2 = bpv;
    }

    const unsigned m0 = 1u << (KBITS - 1 - i0);
    const unsigned m1 = 1u << (KBITS - 1 - i1);
    const unsigned m2 = 1u << (KBITS - 1 - i2);
    base0 = wb & ~(m0 | m1 | m2);
    m0o = m0; m1o = m1; m2o = m2;
    p0o = p0; p1o = p1; p2o = p2;
}

// pixel I of this quad: broadcast its summary, gather 8 words, FMA into acc.
template<int I>
__device__ __forceinline__ void do_px(const float* __restrict__ L, int sl,
                                      unsigned base0, unsigned m0, unsigned m1,
                                      unsigned m2, float p0, float p1, float p2,
                                      float4& acc) {
    const unsigned WB = qb_u<I>(base0);
    const unsigned M0 = qb_u<I>(m0), M1 = qb_u<I>(m1), M2 = qb_u<I>(m2);
    const float   P0 = qb_f<I>(p0),  P1 = qb_f<I>(p1),  P2 = qb_f<I>(p2);
    const float   Q0 = 1.f - P0,     Q1 = 1.f - P1,     Q2 = 1.f - P2;
    #pragma unroll
    for (int a = 0; a < 8; ++a) {
        const unsigned it = WB | ((a & 1) ? M0 : 0u)
                               | ((a & 2) ? M1 : 0u)
                               | ((a & 4) ? M2 : 0u);
        const float at = ((a & 1) ? P0 : Q0) * ((a & 2) ? P1 : Q1)
                       * ((a & 4) ? P2 : Q2);
        const float4 v = *(const float4*)(L + it * 16 + sl * 4);  // 64B chunk
        acc.x = fmaf(at, v.x, acc.x);
        acc.y = fmaf(at, v.y, acc.y);
        acc.z = fmaf(at, v.z, acc.z);
        acc.w = fmaf(at, v.w, acc.w);
    }
}

__global__ __launch_bounds__(1024, 4)
void fern_kernel(const float* __restrict__ B,
                 const float* __restrict__ tables,
                 float* __restrict__ out) {
    __shared__ __align__(16) float lds[2][1024 * 16];   // 2 x 64KB

    const int t    = (int)threadIdx.x;
    const int bid  = (int)blockIdx.x;
    const int dq   = bid >> 6;           // d-quarter: d = dq*16 .. +15
    const int pg   = bid & 63;           // pixel group == image index n
    const int gang = t >> 2;             // 0..255 (hardware quad)
    const int sl   = t & 3;              // 16B slot within the 64B row chunk
    const int qi   = t & 3;              // which of the quad's 4 px this lane owns

    const int px_gang = pg * 1024 + gang * 4;
    const int mypx    = px_gang + qi;
    const int hw      = mypx & 1023;     // mypx>>10 == pg (uniform per block)
    const float* bptr = B + (size_t)pg * (NFERN * KBITS * 1024) + hw;

    const float* tabq = tables + dq * 16;   // this block's d-quarter columns

    float4 acc0 = make_float4(0.f,0.f,0.f,0.f), acc1 = acc0, acc2 = acc0, acc3 = acc0;

    // stage fern m's d-quarter slice (1024 rows x 64B) into lds[buf].
    // dest linear (wave-uniform base + t*16); source: row (t>>2), slot (t&3).
    #define STAGE(mm, buf)                                                      \
        { const float* src_ = tabq + (size_t)(mm) * (1024 * 64);                \
          _Pragma("unroll")                                                     \
          for (int R = 0; R < 4; ++R) {                                         \
              const int row_ = R * 256 + (t >> 2);                              \
              g2lds16(src_ + (size_t)row_ * 64 + (t & 3) * 4,                   \
                      (char*)(&lds[buf][0]) + R * 16384 + t * 16);              \
          } }

    // ---- prologue: stage fern 0; compute fern-0 summary while it flies ----
    unsigned b0, M0, M1, M2;
    float    P0, P1, P2;
    STAGE(0, 0);
    phaseA(bptr, 0, b0, M0, M1, M2, P0, P1, P2);
    __syncthreads();   // vmcnt drained per-wave before barrier -> buf0 ready

    #pragma unroll 1
    for (int m = 0; m < NFERN; ++m) {
        // next-fern work issued in the SAME window as this fern's gathers:
        // STAGE (VMEM->LDS), phaseA(m+1) (VMEM+VALU) vs do_px (LDS+FMA).
        unsigned nb0 = 0, nM0 = 0, nM1 = 0, nM2 = 0;
        float    nP0 = 0.f, nP1 = 0.f, nP2 = 0.f;
        if (m + 1 < NFERN) {
            STAGE(m + 1, (m + 1) & 1);
            phaseA(bptr, m + 1, nb0, nM0, nM1, nM2, nP0, nP1, nP2);
        }

        const float* L = &lds[m & 1][0];
        do_px<0>(L, sl, b0, M0, M1, M2, P0, P1, P2, acc0);
        do_px<1>(L, sl, b0, M0, M1, M2, P0, P1, P2, acc1);
        do_px<2>(L, sl, b0, M0, M1, M2, P0, P1, P2, acc2);
        do_px<3>(L, sl, b0, M0, M1, M2, P0, P1, P2, acc3);

        __syncthreads();   // reads of buf[m&1] done; STAGE(m+1) landed

        b0 = nb0; M0 = nM0; M1 = nM1; M2 = nM2;
        P0 = nP0; P1 = nP1; P2 = nP2;
    }
    #undef STAGE

    // ---- store: quad writes 4x16B = 64B contiguous per pixel ----
    {
        float* op0 = out + (size_t)(px_gang + 0) * 64 + dq * 16 + sl * 4;
        float* op1 = out + (size_t)(px_gang + 1) * 64 + dq * 16 + sl * 4;
        float* op2 = out + (size_t)(px_gang + 2) * 64 + dq * 16 + sl * 4;
        float* op3 = out + (size_t)(px_gang + 3) * 64 + dq * 16 + sl * 4;
        *(float4*)op0 = acc0;
        *(float4*)op1 = acc1;
        *(float4*)op2 = acc2;
        *(float4*)op3 = acc3;
    }
}

extern "C" void kernel_launch(void* const* d_in, const int* in_sizes, int n_in,
                              void* d_out, int out_size, void* d_ws, size_t ws_size,
                              hipStream_t stream) {
    const float* B      = (const float*)d_in[0];
    const float* tables = (const float*)d_in[1];
    float* out          = (float*)d_out;
    fern_kernel<<<dim3(256), dim3(1024), 0, stream>>>(B, tables, out);
}